// Round 2
// baseline (294.403 us; speedup 1.0000x reference)
//
#include <hip/hip_runtime.h>
#include <stdint.h>

// B=16 H=8 L=512 D=64; fp32 in/out. out = concat(output[128,512,64], attn[128,512,512]).
// Round-6: occupancy restructure.
//   Round-5 post-mortem: fetch dropped 140->25MB but time unchanged -> latency-bound
//   at 2 waves/SIMD (acc[32] f32x4 = 128 AGPR + 104 VGPR = 248 regs). Fix:
//   (a) pre-pass kernel converts K->bf16 hi/lo and V->V^T bf16 ONCE into d_ws
//       (kills the 8x-redundant per-block conversion VALU and the 8-way-conflicted
//       LDS V-transpose writes);
//   (b) main kernel: block = 16 q-rows, waves split j (128 each) -> acc = 32 regs
//       -> 4 waves/SIMD; K/V frags load directly from L2-resident ws (no QK LDS,
//       no QK barriers); 3 barriers/block total (2 softmax reduce + 1 O reduce).
#define Ln 512
#define Dn 64
#define BHn 128
#define AOFF ((size_t)BHn*Ln*Dn)

typedef __attribute__((ext_vector_type(8))) short short8;   // 8 bf16 (4 VGPRs)
typedef __attribute__((ext_vector_type(4))) float f32x4;
typedef __attribute__((ext_vector_type(4))) unsigned int u32x4;
typedef __attribute__((ext_vector_type(2))) unsigned int u32x2;

__device__ __forceinline__ uint16_t f2bf(float f){
  uint32_t x = __float_as_uint(f);
  return (uint16_t)((x + 0x7FFFu + ((x>>16)&1u)) >> 16);   // RNE
}
__device__ __forceinline__ float bf2f(uint16_t u){ return __uint_as_float(((uint32_t)u)<<16); }
__device__ __forceinline__ uint32_t pack2(float a, float b){
  return (uint32_t)f2bf(a) | ((uint32_t)f2bf(b)<<16);
}

// ---------------- pre-pass: K -> KHI/KLO bf16 [bh][j][k]; V -> VT bf16 [bh][d][j] ----
extern "C" __global__ __launch_bounds__(256)
void attn_prep(const float* __restrict__ kg, const float* __restrict__ vg,
               uint16_t* __restrict__ khi, uint16_t* __restrict__ klo,
               uint16_t* __restrict__ vt)
{
  const int t  = threadIdx.x;
  const int c  = blockIdx.x;          // j-chunk of 128
  const int bh = blockIdx.y;
  const size_t base = (size_t)bh*(Ln*Dn);

  // K: thread pair per row; skh selects 32-k half (128B)
  {
    const int sj  = t>>1, skh = t&1;
    const float* kr = kg + base + (size_t)(c*128 + sj)*Dn + skh*32;
    uint16_t* dhi = khi + (size_t)bh*(Ln*Dn) + (size_t)(c*128 + sj)*Dn + skh*32;
    uint16_t* dlo = klo + (size_t)bh*(Ln*Dn) + (size_t)(c*128 + sj)*Dn + skh*32;
    #pragma unroll
    for (int w2=0; w2<4; ++w2){
      f32x4 x0 = *(const f32x4*)(kr + w2*8);
      f32x4 x1 = *(const f32x4*)(kr + w2*8 + 4);
      uint32_t hw[4], lw[4];
      #pragma unroll
      for (int pi=0; pi<4; ++pi){
        float a0 = (pi<2) ? x0[pi*2]   : x1[(pi-2)*2];
        float a1 = (pi<2) ? x0[pi*2+1] : x1[(pi-2)*2+1];
        uint16_t h0 = f2bf(a0), h1 = f2bf(a1);
        hw[pi] = (uint32_t)h0 | ((uint32_t)h1<<16);
        lw[pi] = (uint32_t)f2bf(a0 - bf2f(h0)) | ((uint32_t)f2bf(a1 - bf2f(h1))<<16);
      }
      *(u32x4*)(dhi + w2*8) = (u32x4){hw[0],hw[1],hw[2],hw[3]};
      *(u32x4*)(dlo + w2*8) = (u32x4){lw[0],lw[1],lw[2],lw[3]};
    }
  }

  // V: 4x4 register transpose -> VT[bh][d][j]
  #pragma unroll
  for (int it=0; it<2; ++it){
    const int j0 = (t>>4)*4 + it*64;    // [0,128)
    const int d0 = (t&15)*4;
    const float* vr = vg + base + (size_t)(c*128 + j0)*Dn + d0;
    f32x4 r0 = *(const f32x4*)(vr);
    f32x4 r1 = *(const f32x4*)(vr + Dn);
    f32x4 r2 = *(const f32x4*)(vr + 2*Dn);
    f32x4 r3 = *(const f32x4*)(vr + 3*Dn);
    #pragma unroll
    for (int qd=0; qd<4; ++qd){
      u32x2 w; w.x = pack2(r0[qd], r1[qd]); w.y = pack2(r2[qd], r3[qd]);
      *(u32x2*)(vt + (size_t)bh*(Dn*Ln) + (size_t)(d0+qd)*Ln + c*128 + j0) = w;
    }
  }
}

// ---------------- main: block = 16 q-rows; waves split j ----------------
#define PSTRH 152   // PW row stride (halves): 304B = 19*16B, ~2-way banks

extern "C" __global__ __launch_bounds__(256, 4)
void attn_main(const float* __restrict__ qg, const float* __restrict__ mg,
               const uint16_t* __restrict__ khi, const uint16_t* __restrict__ klo,
               const uint16_t* __restrict__ vt, float* __restrict__ outg)
{
  // LDS: PW 4x16x152 halves (19456B) | OR 4x1088 f32 (17408B) | MXW 64 f32 | SMW 64 f32
  __shared__ uint4 lds2[37376/16];
  uint16_t* PW  = (uint16_t*)lds2;
  float*    OR_ = (float*)((char*)lds2 + 19456);
  float*    MXW = (float*)((char*)lds2 + 19456 + 17408);
  float*    SMW = MXW + 64;

  const int t    = threadIdx.x;
  const int lane = t & 63;
  const int wv   = t >> 6;
  const int li   = lane & 15;
  const int lq   = lane >> 4;

  // XCD-aware swizzle: lin%8 = XCD; XCD k owns bh [k*16,k*16+16) x 32 i-tiles.
  const int lin   = blockIdx.x + (blockIdx.y << 5);   // gridDim.x = 32
  const int xcd   = lin & 7;
  const int jj    = lin >> 3;                          // [0,512)
  const int bh    = (xcd << 4) + (jj >> 5);
  const int itile = jj & 31;
  const int b     = bh >> 3;
  const int i0    = itile*16;
  const int wj0   = wv*128;                            // wave's j-window

  const size_t base = (size_t)bh*(Ln*Dn);
  const float* mrow = mg + b*Ln;
  uint16_t* PWme = PW + wv*(16*PSTRH);

  // ---- Q fragments hi/lo (B operand; all 4 waves use the same 16 rows) ----
  short8 qhi[2], qlo[2];
  {
    const float* qrow = qg + base + (size_t)(i0 + li)*Dn;
    #pragma unroll
    for (int kt=0; kt<2; ++kt){
      const float* p = qrow + kt*32 + lq*8;
      f32x4 x0 = *(const f32x4*)p;
      f32x4 x1 = *(const f32x4*)(p+4);
      #pragma unroll
      for (int e=0; e<8; ++e){
        float x = (e<4) ? x0[e] : x1[e-4];
        uint16_t h = f2bf(x);
        qhi[kt][e] = (short)h;
        qlo[kt][e] = (short)f2bf(x - bf2f(h));
      }
    }
  }

  // ---- S^T = K Q^T over wave's 128-j window; K frags straight from ws (L2) ----
  f32x4 acc[8];
  #pragma unroll
  for (int j=0; j<8; ++j) acc[j] = (f32x4)0.f;

  const uint16_t* khb = khi + (size_t)bh*(Ln*Dn) + (size_t)wj0*Dn;
  const uint16_t* klb = klo + (size_t)bh*(Ln*Dn) + (size_t)wj0*Dn;
  #pragma unroll
  for (int jt=0; jt<8; ++jt){
    const int ro = (jt*16 + li)*Dn;
    #pragma unroll
    for (int kt=0; kt<2; ++kt){
      short8 kh = *(const short8*)(khb + ro + kt*32 + lq*8);
      short8 kl = *(const short8*)(klb + ro + kt*32 + lq*8);
      f32x4 A = acc[jt];
      A = __builtin_amdgcn_mfma_f32_16x16x32_bf16(kh, qhi[kt], A, 0,0,0);
      A = __builtin_amdgcn_mfma_f32_16x16x32_bf16(kl, qhi[kt], A, 0,0,0);
      A = __builtin_amdgcn_mfma_f32_16x16x32_bf16(kh, qlo[kt], A, 0,0,0);
      acc[jt] = A;
    }
  }

  // ---- mask + scale (fp32 order matches ref) ----
  {
    float mv = mrow[i0 + li];
    const float rmv = (mv < -9000.f) ? 1e9f : mv;
    #pragma unroll
    for (int jt=0; jt<8; ++jt){
      f32x4 cmr = *(const f32x4*)(mrow + wj0 + jt*16 + lq*4);
      #pragma unroll
      for (int r=0; r<4; ++r){
        float cm = (cmr[r] < -9000.f) ? 1e9f : cmr[r];
        acc[jt][r] = (acc[jt][r]*0.125f - rmv) - cm;
      }
    }
  }

  // ---- softmax: wave-local reduce over 128 j, then cross-wave via LDS ----
  float mx = -3.4e38f;
  #pragma unroll
  for (int jt=0; jt<8; ++jt)
    #pragma unroll
    for (int r=0; r<4; ++r) mx = fmaxf(mx, acc[jt][r]);
  mx = fmaxf(mx, __shfl_xor(mx, 16));
  mx = fmaxf(mx, __shfl_xor(mx, 32));
  if (lane < 16) MXW[wv*16 + lane] = mx;
  __syncthreads();
  const float mxa = fmaxf(fmaxf(MXW[li], MXW[16+li]), fmaxf(MXW[32+li], MXW[48+li]));

  float sum = 0.f;
  #pragma unroll
  for (int jt=0; jt<8; ++jt)
    #pragma unroll
    for (int r=0; r<4; ++r){ float e = __expf(acc[jt][r]-mxa); acc[jt][r] = e; sum += e; }
  sum += __shfl_xor(sum, 16);
  sum += __shfl_xor(sum, 32);
  if (lane < 16) SMW[wv*16 + lane] = sum;
  __syncthreads();
  const float inv = 1.0f/((SMW[li] + SMW[16+li]) + (SMW[32+li] + SMW[48+li]));

  // ---- normalize + write attn (nontemporal; rows i0+li, cols wj0+jt*16+lq*4) ----
  {
    float* arow = outg + AOFF + (size_t)bh*Ln*Ln + (size_t)(i0+li)*Ln + wj0;
    #pragma unroll
    for (int jt=0; jt<8; ++jt){
      f32x4 p = acc[jt]*inv;
      acc[jt] = p;
      __builtin_nontemporal_store(p, (f32x4*)(arow + jt*16 + lq*4));
    }
  }

  // ---- P round-trip through per-wave private LDS (bf16), then PV ----
  #pragma unroll
  for (int jtl=0; jtl<8; ++jtl){
    const f32x4 p = acc[jtl];
    u32x2 w; w.x = pack2(p[0], p[1]); w.y = pack2(p[2], p[3]);
    *(u32x2*)(PWme + li*PSTRH + jtl*16 + lq*4) = w;
  }
  asm volatile("s_waitcnt lgkmcnt(0)" ::: "memory");

  f32x4 oacc[4];
  #pragma unroll
  for (int dt=0; dt<4; ++dt) oacc[dt] = (f32x4)0.f;

  const uint16_t* vtb = vt + (size_t)bh*(Dn*Ln) + wj0;
  #pragma unroll
  for (int c32=0; c32<4; ++c32){
    short8 pf = *(const short8*)(PWme + li*PSTRH + c32*32 + lq*8);     // P^T B-frag
    #pragma unroll
    for (int dt=0; dt<4; ++dt){
      short8 vb = *(const short8*)(vtb + (size_t)(dt*16+li)*Ln + c32*32 + lq*8); // V^T A-frag
      oacc[dt] = __builtin_amdgcn_mfma_f32_16x16x32_bf16(vb, pf, oacc[dt], 0,0,0);
    }
  }

  // ---- cross-wave O reduce: OR[wv][d*17+i] (pad 17 breaks bank alignment) ----
  #pragma unroll
  for (int dt=0; dt<4; ++dt)
    #pragma unroll
    for (int r=0; r<4; ++r)
      OR_[wv*1088 + (dt*16 + lq*4 + r)*17 + li] = oacc[dt][r];
  __syncthreads();
  #pragma unroll
  for (int k=0; k<4; ++k){
    const int o = t + 256*k;          // [0,1024): d = o>>4, i = o&15
    const int d = o >> 4, i = o & 15;
    const int x = d*17 + i;
    float s = (OR_[x] + OR_[1088 + x]) + (OR_[2176 + x] + OR_[3264 + x]);
    outg[base + (size_t)(i0 + i)*Dn + d] = s;
  }
}

// ---------------- fallback (round-5 kernel) if workspace is too small ----------------
#define KSTR  72
#define VTSTR 136
#define FPSTRH 136

extern "C" __global__ __launch_bounds__(256, 2)
void attn_mfma(const float* __restrict__ qg, const float* __restrict__ kg,
               const float* __restrict__ vg, const float* __restrict__ mg,
               float* __restrict__ outg)
{
  __shared__ uint4 ldsraw[(36864 + 2048)/16];
  uint16_t* KHI = (uint16_t*)ldsraw;
  uint16_t* KLO = KHI + 128*KSTR;
  uint16_t* VT  = (uint16_t*)ldsraw;
  float*    CMV = (float*)((char*)ldsraw + 36864);

  const int t    = threadIdx.x;
  const int lane = t & 63;
  const int wv   = t >> 6;
  const int li   = lane & 15;
  const int lq   = lane >> 4;

  const int lin = blockIdx.x + (blockIdx.y << 3);
  const int xcd = lin & 7;
  const int jj  = lin >> 3;
  const int bh  = (xcd << 4) + (jj >> 3);
  const int b   = bh >> 3;
  const int i0  = (jj & 7)*64 + wv*16;

  const size_t base = (size_t)bh*(Ln*Dn);
  const float* mrow = mg + b*Ln;

  uint16_t* PW = (uint16_t*)((char*)ldsraw + 17408 + wv*(16*FPSTRH*2));

  {
    float m0 = mrow[t], m1 = mrow[t+256];
    CMV[t]     = (m0 < -9000.f) ? 1e9f : m0;
    CMV[t+256] = (m1 < -9000.f) ? 1e9f : m1;
  }

  short8 qhi[2], qlo[2];
  {
    const float* qrow = qg + base + (size_t)(i0 + li)*Dn;
    #pragma unroll
    for (int kt=0; kt<2; ++kt){
      const float* p = qrow + kt*32 + lq*8;
      f32x4 x0 = *(const f32x4*)p;
      f32x4 x1 = *(const f32x4*)(p+4);
      #pragma unroll
      for (int e=0; e<8; ++e){
        float x = (e<4) ? x0[e] : x1[e-4];
        uint16_t h = f2bf(x);
        qhi[kt][e] = (short)h;
        qlo[kt][e] = (short)f2bf(x - bf2f(h));
      }
    }
  }

  f32x4 acc[32];
  #pragma unroll
  for (int j=0; j<32; ++j) acc[j] = (f32x4)0.f;

  const int sj = t>>1, skh = t&1;
  #pragma unroll
  for (int c=0; c<4; ++c){
    __syncthreads();
    {
      const float* kr = kg + base + (size_t)(c*128 + sj)*Dn + skh*32;
      uint16_t* dhi = KHI + sj*KSTR + skh*32;
      uint16_t* dlo = KLO + sj*KSTR + skh*32;
      #pragma unroll
      for (int w2=0; w2<4; ++w2){
        f32x4 x0 = *(const f32x4*)(kr + w2*8);
        f32x4 x1 = *(const f32x4*)(kr + w2*8 + 4);
        uint32_t hw[4], lw[4];
        #pragma unroll
        for (int pi=0; pi<4; ++pi){
          float a0 = (pi<2) ? x0[pi*2]   : x1[(pi-2)*2];
          float a1 = (pi<2) ? x0[pi*2+1] : x1[(pi-2)*2+1];
          uint16_t h0 = f2bf(a0), h1 = f2bf(a1);
          hw[pi] = (uint32_t)h0 | ((uint32_t)h1<<16);
          lw[pi] = (uint32_t)f2bf(a0 - bf2f(h0)) | ((uint32_t)f2bf(a1 - bf2f(h1))<<16);
        }
        *(u32x4*)(dhi + w2*8) = (u32x4){hw[0],hw[1],hw[2],hw[3]};
        *(u32x4*)(dlo + w2*8) = (u32x4){lw[0],lw[1],lw[2],lw[3]};
      }
    }
    __syncthreads();
    #pragma unroll
    for (int jt=0; jt<8; ++jt){
      #pragma unroll
      for (int kt=0; kt<2; ++kt){
        const int off = (jt*16 + li)*KSTR + kt*32 + lq*8;
        short8 kh = *(const short8*)(KHI + off);
        short8 kl = *(const short8*)(KLO + off);
        f32x4 A = acc[c*8+jt];
        A = __builtin_amdgcn_mfma_f32_16x16x32_bf16(kh, qhi[kt], A, 0,0,0);
        A = __builtin_amdgcn_mfma_f32_16x16x32_bf16(kl, qhi[kt], A, 0,0,0);
        A = __builtin_amdgcn_mfma_f32_16x16x32_bf16(kh, qlo[kt], A, 0,0,0);
        acc[c*8+jt] = A;
      }
    }
  }

  {
    float mv = mrow[i0 + li];
    const float rmv = (mv < -9000.f) ? 1e9f : mv;
    #pragma unroll
    for (int jt=0; jt<32; ++jt){
      f32x4 cm = *(const f32x4*)(CMV + jt*16 + lq*4);
      #pragma unroll
      for (int r=0; r<4; ++r)
        acc[jt][r] = (acc[jt][r]*0.125f - rmv) - cm[r];
    }
  }
  float mx = -3.4e38f;
  #pragma unroll
  for (int jt=0; jt<32; ++jt)
    #pragma unroll
    for (int r=0; r<4; ++r) mx = fmaxf(mx, acc[jt][r]);
  mx = fmaxf(mx, __shfl_xor(mx, 16));
  mx = fmaxf(mx, __shfl_xor(mx, 32));
  float sum = 0.f;
  #pragma unroll
  for (int jt=0; jt<32; ++jt)
    #pragma unroll
    for (int r=0; r<4; ++r){ float e = __expf(acc[jt][r]-mx); acc[jt][r] = e; sum += e; }
  sum += __shfl_xor(sum, 16);
  sum += __shfl_xor(sum, 32);
  const float inv = 1.0f/sum;

  {
    float* arow = outg + AOFF + (size_t)bh*Ln*Ln + (size_t)(i0+li)*Ln;
    #pragma unroll
    for (int jt=0; jt<32; ++jt){
      f32x4 p = acc[jt]*inv;
      acc[jt] = p;
      *(f32x4*)(arow + jt*16 + lq*4) = p;
    }
  }

  f32x4 oacc[4];
  #pragma unroll
  for (int dt=0; dt<4; ++dt) oacc[dt] = (f32x4)0.f;

  #pragma unroll
  for (int c=0; c<4; ++c){
    __syncthreads();
    #pragma unroll
    for (int it=0; it<2; ++it){
      const int j0 = (t>>4)*4 + it*64;
      const int d0 = (t&15)*4;
      const float* vr = vg + base + (size_t)(c*128 + j0)*Dn + d0;
      f32x4 r0 = *(const f32x4*)(vr);
      f32x4 r1 = *(const f32x4*)(vr + Dn);
      f32x4 r2 = *(const f32x4*)(vr + 2*Dn);
      f32x4 r3 = *(const f32x4*)(vr + 3*Dn);
      #pragma unroll
      for (int qd=0; qd<4; ++qd){
        u32x2 w; w.x = pack2(r0[qd], r1[qd]); w.y = pack2(r2[qd], r3[qd]);
        *(u32x2*)(VT + (d0+qd)*VTSTR + j0) = w;
      }
    }
    __syncthreads();
    #pragma unroll
    for (int jtl=0; jtl<8; ++jtl){
      const f32x4 p = acc[c*8+jtl];
      u32x2 w; w.x = pack2(p[0], p[1]); w.y = pack2(p[2], p[3]);
      *(u32x2*)(PW + li*FPSTRH + jtl*16 + lq*4) = w;
    }
    asm volatile("s_waitcnt lgkmcnt(0)" ::: "memory");
    #pragma unroll
    for (int c32=0; c32<4; ++c32){
      short8 pf = *(const short8*)(PW + li*FPSTRH + c32*32 + lq*8);
      #pragma unroll
      for (int dt=0; dt<4; ++dt){
        short8 vb = *(const short8*)(VT + (dt*16+li)*VTSTR + c32*32 + lq*8);
        oacc[dt] = __builtin_amdgcn_mfma_f32_16x16x32_bf16(vb, pf, oacc[dt], 0,0,0);
      }
    }
  }

  #pragma unroll
  for (int dt=0; dt<4; ++dt)
    *(f32x4*)(outg + base + (size_t)(i0+li)*Dn + dt*16 + lq*4) = oacc[dt];
}

extern "C" void kernel_launch(void* const* d_in, const int* in_sizes, int n_in,
                              void* d_out, int out_size, void* d_ws, size_t ws_size,
                              hipStream_t stream)
{
  (void)in_sizes; (void)n_in; (void)out_size;
  const float* qg = (const float*)d_in[0];
  const float* kg = (const float*)d_in[1];
  const float* vg = (const float*)d_in[2];
  const float* mg = (const float*)d_in[3];
  float* outg = (float*)d_out;

  const size_t WS_NEED = 25165824;   // KHI 8.39MB + KLO 8.39MB + VT 8.39MB
  if (d_ws && ws_size >= WS_NEED){
    uint16_t* khi = (uint16_t*)d_ws;
    uint16_t* klo = (uint16_t*)((char*)d_ws + 8388608);
    uint16_t* vt  = (uint16_t*)((char*)d_ws + 16777216);
    attn_prep<<<dim3(4, BHn), 256, 0, stream>>>(kg, vg, khi, klo, vt);
    attn_main<<<dim3(32, BHn), 256, 0, stream>>>(qg, mg, khi, klo, vt, outg);
  } else {
    attn_mfma<<<dim3(Ln/64, BHn), 256, 0, stream>>>(qg, kg, vg, mg, outg);
  }
}

// Round 3
// 233.195 us; speedup vs baseline: 1.2625x; 1.2625x over previous
//
#include <hip/hip_runtime.h>
#include <stdint.h>

// B=16 H=8 L=512 D=64; fp32 in/out. out = concat(output[128,512,64], attn[128,512,512]).
// Round-7: round-5 block shape (64 q-rows, K/V read once per block) + prep kernel
// emitting bf16 hi/lo K and V^T PRE-SWIZZLED in ws + global_load_lds DMA staging
// (zero VALU, conflict-free) + double-buffered chunks with raw s_barrier and
// counted vmcnt(8) so next-chunk DMA stays in flight across barriers (T3+T4).
// Phase order: QK -> softmax -> PV -> O -> attn-write (keeps PV vmcnt ledger clean).
#define Ln 512
#define Dn 64
#define BHn 128
#define AOFF ((size_t)BHn*Ln*Dn)

typedef __attribute__((ext_vector_type(8))) short short8;   // 8 bf16 (4 VGPRs)
typedef __attribute__((ext_vector_type(4))) float f32x4;
typedef __attribute__((ext_vector_type(4))) unsigned int u32x4;
typedef __attribute__((ext_vector_type(2))) unsigned int u32x2;

__device__ __forceinline__ uint16_t f2bf(float f){
  uint32_t x = __float_as_uint(f);
  return (uint16_t)((x + 0x7FFFu + ((x>>16)&1u)) >> 16);   // RNE
}
__device__ __forceinline__ float bf2f(uint16_t u){ return __uint_as_float(((uint32_t)u)<<16); }
__device__ __forceinline__ uint32_t pack2(float a, float b){
  return (uint32_t)f2bf(a) | ((uint32_t)f2bf(b)<<16);
}
__device__ __forceinline__ void gld16(const uint16_t* g, uint16_t* l){
  __builtin_amdgcn_global_load_lds(
      (const __attribute__((address_space(1))) void*)g,
      (__attribute__((address_space(3))) void*)l, 16, 0, 0);
}

// ---- pre-pass: K -> KHI/KLO bf16, V -> V^T bf16, XOR-swizzled, chunk-major in ws ----
// K chunk layout (halves, per bh per chunk of 128 j): idx = j*64 + (k ^ ((j&7)<<3))
// V chunk layout (halves): idx = d*128 + (jl ^ ((d&7)<<3)), jl = j within chunk
extern "C" __global__ __launch_bounds__(256)
void attn_prep(const float* __restrict__ kg, const float* __restrict__ vg,
               uint16_t* __restrict__ khw, uint16_t* __restrict__ klw,
               uint16_t* __restrict__ vtw)
{
  const int t  = threadIdx.x;
  const int c  = blockIdx.x;          // j-chunk of 128
  const int bh = blockIdx.y;
  const size_t base = (size_t)bh*(Ln*Dn);
  const size_t wsb  = ((size_t)bh<<15) + ((size_t)c<<13);   // chunk base (halves)

  // K: thread pair per row; skh selects 32-k half
  {
    const int sj  = t>>1, skh = t&1;
    const float* kr = kg + base + (size_t)(c*128 + sj)*Dn + skh*32;
    const int sx = (sj&7)<<3;
    #pragma unroll
    for (int w2=0; w2<4; ++w2){
      f32x4 x0 = *(const f32x4*)(kr + w2*8);
      f32x4 x1 = *(const f32x4*)(kr + w2*8 + 4);
      uint32_t hw[4], lw[4];
      #pragma unroll
      for (int pi=0; pi<4; ++pi){
        float a0 = (pi<2) ? x0[pi*2]   : x1[(pi-2)*2];
        float a1 = (pi<2) ? x0[pi*2+1] : x1[(pi-2)*2+1];
        uint16_t h0 = f2bf(a0), h1 = f2bf(a1);
        hw[pi] = (uint32_t)h0 | ((uint32_t)h1<<16);
        lw[pi] = (uint32_t)f2bf(a0 - bf2f(h0)) | ((uint32_t)f2bf(a1 - bf2f(h1))<<16);
      }
      const size_t di = wsb + sj*64 + ((skh*32 + w2*8) ^ sx);   // 8-aligned block, XOR keeps it contiguous
      *(u32x4*)(khw + di) = (u32x4){hw[0],hw[1],hw[2],hw[3]};
      *(u32x4*)(klw + di) = (u32x4){lw[0],lw[1],lw[2],lw[3]};
    }
  }

  // V: 4x4 register transpose -> VT[d][jl], swizzled
  #pragma unroll
  for (int it=0; it<2; ++it){
    const int j0 = (t>>4)*4 + it*64;    // [0,128)
    const int d0 = (t&15)*4;
    const float* vr = vg + base + (size_t)(c*128 + j0)*Dn + d0;
    f32x4 r0 = *(const f32x4*)(vr);
    f32x4 r1 = *(const f32x4*)(vr + Dn);
    f32x4 r2 = *(const f32x4*)(vr + 2*Dn);
    f32x4 r3 = *(const f32x4*)(vr + 3*Dn);
    #pragma unroll
    for (int qd=0; qd<4; ++qd){
      const int d = d0 + qd;
      u32x2 w; w.x = pack2(r0[qd], r1[qd]); w.y = pack2(r2[qd], r3[qd]);
      *(u32x2*)(vtw + wsb + d*128 + (j0 ^ ((d&7)<<3))) = w;   // j0 4-aligned, XOR bits 3-5
    }
  }
}

// ---- main: 64 q-rows/block, 4 waves x 16 rows; DMA-staged dbuf chunks ----
extern "C" __global__ __launch_bounds__(256, 2)
void attn_main2(const float* __restrict__ qg, const float* __restrict__ mg,
                const uint16_t* __restrict__ khw, const uint16_t* __restrict__ klw,
                const uint16_t* __restrict__ vtw, float* __restrict__ outg)
{
  // 64KB: QK phase KH0[8192] KL0[8192] KH1[8192] KL1[8192] (halves)
  //       PV phase VT0[8192] VT1[8192] P[4 waves][2176]
  __shared__ __align__(16) uint16_t BIG[32768];

  const int t    = threadIdx.x;
  const int lane = t & 63;
  const int wv   = t >> 6;
  const int li   = lane & 15;
  const int lq   = lane >> 4;
  const int kx   = (li&7)<<3;          // swizzle XOR (halves)

  // XCD swizzle (round-5): lin%8 = XCD; XCD k owns bh [k*16,k*16+16)
  const int lin = blockIdx.x + (blockIdx.y << 3);
  const int xcd = lin & 7;
  const int jj  = lin >> 3;
  const int bh  = (xcd << 4) + (jj >> 3);
  const int b   = bh >> 3;
  const int i0  = (jj & 7)*64 + wv*16;

  const size_t base = (size_t)bh*(Ln*Dn);
  const float* mrow = mg + b*Ln;
  const size_t wsbh = (size_t)bh << 15;

  uint16_t* PW = BIG + 16384 + wv*2176;

  // DMA issue: K chunk c -> buffer bsel (8 ops/wave), V chunk c -> bsel (4 ops/wave)
  auto issueK = [&](int c, int bsel){
    const size_t so = wsbh + ((size_t)c<<13) + (wv<<11) + (lane<<3);
    uint16_t* dh = BIG + bsel*16384 + (wv<<11);
    #pragma unroll
    for (int i=0;i<4;++i){
      gld16(khw + so + i*512, dh + i*512);
      gld16(klw + so + i*512, dh + 8192 + i*512);
    }
  };
  auto issueV = [&](int c, int bsel){
    const size_t so = wsbh + ((size_t)c<<13) + (wv<<11) + (lane<<3);
    uint16_t* dv = BIG + bsel*8192 + (wv<<11);
    #pragma unroll
    for (int i=0;i<4;++i) gld16(vtw + so + i*512, dv + i*512);
  };

  issueK(0, 0);   // prologue DMA overlaps Q load+convert

  // ---- Q fragments hi/lo (B operand; lane li holds Q[i0+li][kt*32+lq*8+e]) ----
  short8 qhi[2], qlo[2];
  {
    const float* qrow = qg + base + (size_t)(i0 + li)*Dn;
    #pragma unroll
    for (int kt=0; kt<2; ++kt){
      const float* p = qrow + kt*32 + lq*8;
      f32x4 x0 = *(const f32x4*)p;
      f32x4 x1 = *(const f32x4*)(p+4);
      #pragma unroll
      for (int e=0; e<8; ++e){
        float x = (e<4) ? x0[e] : x1[e-4];
        uint16_t h = f2bf(x);
        qhi[kt][e] = (short)h;
        qlo[kt][e] = (short)f2bf(x - bf2f(h));
      }
    }
  }

  f32x4 acc[32];
  #pragma unroll
  for (int j=0; j<32; ++j) acc[j] = (f32x4)0.f;

  // ---- QK: 4 chunks, double-buffered DMA; raw barriers + counted vmcnt ----
  #pragma unroll
  for (int c=0; c<4; ++c){
    if (c<3) issueK(c+1, (c+1)&1);
    if (c<3) asm volatile("s_waitcnt vmcnt(8)" ::: "memory");   // chunk c landed (mine)
    else     asm volatile("s_waitcnt vmcnt(0)" ::: "memory");
    __builtin_amdgcn_sched_barrier(0);
    __builtin_amdgcn_s_barrier();                                // all waves' portions landed
    __builtin_amdgcn_sched_barrier(0);
    const uint16_t* KHp = BIG + (c&1)*16384;
    const uint16_t* KLp = KHp + 8192;
    #pragma unroll
    for (int jt=0; jt<8; ++jt){
      #pragma unroll
      for (int kt=0; kt<2; ++kt){
        const int idx = (jt*16 + li)*64 + ((kt*32 + lq*8) ^ kx);
        short8 kh = *(const short8*)(KHp + idx);
        short8 kl = *(const short8*)(KLp + idx);
        f32x4 A = acc[c*8+jt];
        A = __builtin_amdgcn_mfma_f32_16x16x32_bf16(kh, qhi[kt], A, 0,0,0);
        A = __builtin_amdgcn_mfma_f32_16x16x32_bf16(kl, qhi[kt], A, 0,0,0);
        A = __builtin_amdgcn_mfma_f32_16x16x32_bf16(kh, qlo[kt], A, 0,0,0);
        acc[c*8+jt] = A;
      }
    }
    __builtin_amdgcn_sched_barrier(0);
    __builtin_amdgcn_s_barrier();                                // readers done before buf reuse
    __builtin_amdgcn_sched_barrier(0);
  }

  issueV(0, 0);   // VT0 DMA overlaps softmax (K region free after final barrier)

  // ---- mask + scale (fp32 order matches ref) ----
  {
    float mv = mrow[i0 + li];
    const float rmv = (mv < -9000.f) ? 1e9f : mv;
    #pragma unroll
    for (int jt=0; jt<32; ++jt){
      f32x4 cmr = *(const f32x4*)(mrow + jt*16 + lq*4);
      #pragma unroll
      for (int r=0; r<4; ++r){
        float cm = (cmr[r] < -9000.f) ? 1e9f : cmr[r];
        acc[jt][r] = (acc[jt][r]*0.125f - rmv) - cm;
      }
    }
  }

  // ---- softmax over j (wave-local: lane owns full row across quads) ----
  float mx = -3.4e38f;
  #pragma unroll
  for (int jt=0; jt<32; ++jt)
    #pragma unroll
    for (int r=0; r<4; ++r) mx = fmaxf(mx, acc[jt][r]);
  mx = fmaxf(mx, __shfl_xor(mx, 16));
  mx = fmaxf(mx, __shfl_xor(mx, 32));
  float sum = 0.f;
  #pragma unroll
  for (int jt=0; jt<32; ++jt)
    #pragma unroll
    for (int r=0; r<4; ++r){ float e = __expf(acc[jt][r]-mx); acc[jt][r] = e; sum += e; }
  sum += __shfl_xor(sum, 16);
  sum += __shfl_xor(sum, 32);
  const float inv = 1.0f/sum;
  #pragma unroll
  for (int jt=0; jt<32; ++jt) acc[jt] = acc[jt]*inv;   // normalized P (also attn output)

  // ---- PV: O^T = V^T P^T; VT dbuf DMA, P via per-wave private LDS ----
  f32x4 oacc[4];
  #pragma unroll
  for (int dt=0; dt<4; ++dt) oacc[dt] = (f32x4)0.f;

  #pragma unroll
  for (int c=0; c<4; ++c){
    asm volatile("s_waitcnt vmcnt(0)" ::: "memory");   // VT chunk c landed (mine)
    __builtin_amdgcn_sched_barrier(0);
    __builtin_amdgcn_s_barrier();                       // all waves; also gates buf reuse
    __builtin_amdgcn_sched_barrier(0);
    if (c<3) issueV(c+1, (c+1)&1);
    #pragma unroll
    for (int jtl=0; jtl<8; ++jtl){                      // P chunk rows (wave-private)
      const f32x4 p = acc[c*8+jtl];
      u32x2 w; w.x = pack2(p[0], p[1]); w.y = pack2(p[2], p[3]);
      *(u32x2*)(PW + li*136 + jtl*16 + lq*4) = w;
    }
    asm volatile("s_waitcnt lgkmcnt(0)" ::: "memory");  // P visible within wave
    __builtin_amdgcn_sched_barrier(0);
    const uint16_t* VTp = BIG + (c&1)*8192;
    #pragma unroll
    for (int c32=0; c32<4; ++c32){
      short8 pf = *(const short8*)(PW + li*136 + c32*32 + lq*8);           // P^T B-frag
      #pragma unroll
      for (int dt=0; dt<4; ++dt){
        short8 vb = *(const short8*)(VTp + (dt*16+li)*128 + ((c32*32+lq*8) ^ kx)); // V^T A-frag
        oacc[dt] = __builtin_amdgcn_mfma_f32_16x16x32_bf16(vb, pf, oacc[dt], 0,0,0);
      }
    }
  }

  // ---- store O (O^T C-layout) ----
  #pragma unroll
  for (int dt=0; dt<4; ++dt)
    *(f32x4*)(outg + base + (size_t)(i0+li)*Dn + dt*16 + lq*4) = oacc[dt];

  // ---- attn write last (nontemporal; never re-read, keeps ws L2-resident) ----
  {
    float* arow = outg + AOFF + (size_t)bh*Ln*Ln + (size_t)(i0+li)*Ln;
    #pragma unroll
    for (int jt=0; jt<32; ++jt)
      __builtin_nontemporal_store(acc[jt], (f32x4*)(arow + jt*16 + lq*4));
  }
}

// ---------------- fallback (round-5 kernel) if workspace is too small ----------------
#define KSTR  72
#define VTSTR 136
#define FPSTRH 136

extern "C" __global__ __launch_bounds__(256, 2)
void attn_mfma(const float* __restrict__ qg, const float* __restrict__ kg,
               const float* __restrict__ vg, const float* __restrict__ mg,
               float* __restrict__ outg)
{
  __shared__ uint4 ldsraw[(36864 + 2048)/16];
  uint16_t* KHI = (uint16_t*)ldsraw;
  uint16_t* KLO = KHI + 128*KSTR;
  uint16_t* VT  = (uint16_t*)ldsraw;
  float*    CMV = (float*)((char*)ldsraw + 36864);

  const int t    = threadIdx.x;
  const int lane = t & 63;
  const int wv   = t >> 6;
  const int li   = lane & 15;
  const int lq   = lane >> 4;

  const int lin = blockIdx.x + (blockIdx.y << 3);
  const int xcd = lin & 7;
  const int jj  = lin >> 3;
  const int bh  = (xcd << 4) + (jj >> 3);
  const int b   = bh >> 3;
  const int i0  = (jj & 7)*64 + wv*16;

  const size_t base = (size_t)bh*(Ln*Dn);
  const float* mrow = mg + b*Ln;

  uint16_t* PW = (uint16_t*)((char*)ldsraw + 17408 + wv*(16*FPSTRH*2));

  {
    float m0 = mrow[t], m1 = mrow[t+256];
    CMV[t]     = (m0 < -9000.f) ? 1e9f : m0;
    CMV[t+256] = (m1 < -9000.f) ? 1e9f : m1;
  }

  short8 qhi[2], qlo[2];
  {
    const float* qrow = qg + base + (size_t)(i0 + li)*Dn;
    #pragma unroll
    for (int kt=0; kt<2; ++kt){
      const float* p = qrow + kt*32 + lq*8;
      f32x4 x0 = *(const f32x4*)p;
      f32x4 x1 = *(const f32x4*)(p+4);
      #pragma unroll
      for (int e=0; e<8; ++e){
        float x = (e<4) ? x0[e] : x1[e-4];
        uint16_t h = f2bf(x);
        qhi[kt][e] = (short)h;
        qlo[kt][e] = (short)f2bf(x - bf2f(h));
      }
    }
  }

  f32x4 acc[32];
  #pragma unroll
  for (int j=0; j<32; ++j) acc[j] = (f32x4)0.f;

  const int sj = t>>1, skh = t&1;
  #pragma unroll
  for (int c=0; c<4; ++c){
    __syncthreads();
    {
      const float* kr = kg + base + (size_t)(c*128 + sj)*Dn + skh*32;
      uint16_t* dhi = KHI + sj*KSTR + skh*32;
      uint16_t* dlo = KLO + sj*KSTR + skh*32;
      #pragma unroll
      for (int w2=0; w2<4; ++w2){
        f32x4 x0 = *(const f32x4*)(kr + w2*8);
        f32x4 x1 = *(const f32x4*)(kr + w2*8 + 4);
        uint32_t hw[4], lw[4];
        #pragma unroll
        for (int pi=0; pi<4; ++pi){
          float a0 = (pi<2) ? x0[pi*2]   : x1[(pi-2)*2];
          float a1 = (pi<2) ? x0[pi*2+1] : x1[(pi-2)*2+1];
          uint16_t h0 = f2bf(a0), h1 = f2bf(a1);
          hw[pi] = (uint32_t)h0 | ((uint32_t)h1<<16);
          lw[pi] = (uint32_t)f2bf(a0 - bf2f(h0)) | ((uint32_t)f2bf(a1 - bf2f(h1))<<16);
        }
        *(u32x4*)(dhi + w2*8) = (u32x4){hw[0],hw[1],hw[2],hw[3]};
        *(u32x4*)(dlo + w2*8) = (u32x4){lw[0],lw[1],lw[2],lw[3]};
      }
    }
    __syncthreads();
    #pragma unroll
    for (int jt=0; jt<8; ++jt){
      #pragma unroll
      for (int kt=0; kt<2; ++kt){
        const int off = (jt*16 + li)*KSTR + kt*32 + lq*8;
        short8 kh = *(const short8*)(KHI + off);
        short8 kl = *(const short8*)(KLO + off);
        f32x4 A = acc[c*8+jt];
        A = __builtin_amdgcn_mfma_f32_16x16x32_bf16(kh, qhi[kt], A, 0,0,0);
        A = __builtin_amdgcn_mfma_f32_16x16x32_bf16(kl, qhi[kt], A, 0,0,0);
        A = __builtin_amdgcn_mfma_f32_16x16x32_bf16(kh, qlo[kt], A, 0,0,0);
        acc[c*8+jt] = A;
      }
    }
  }

  {
    float mv = mrow[i0 + li];
    const float rmv = (mv < -9000.f) ? 1e9f : mv;
    #pragma unroll
    for (int jt=0; jt<32; ++jt){
      f32x4 cm = *(const f32x4*)(CMV + jt*16 + lq*4);
      #pragma unroll
      for (int r=0; r<4; ++r)
        acc[jt][r] = (acc[jt][r]*0.125f - rmv) - cm[r];
    }
  }
  float mx = -3.4e38f;
  #pragma unroll
  for (int jt=0; jt<32; ++jt)
    #pragma unroll
    for (int r=0; r<4; ++r) mx = fmaxf(mx, acc[jt][r]);
  mx = fmaxf(mx, __shfl_xor(mx, 16));
  mx = fmaxf(mx, __shfl_xor(mx, 32));
  float sum = 0.f;
  #pragma unroll
  for (int jt=0; jt<32; ++jt)
    #pragma unroll
    for (int r=0; r<4; ++r){ float e = __expf(acc[jt][r]-mx); acc[jt][r] = e; sum += e; }
  sum += __shfl_xor(sum, 16);
  sum += __shfl_xor(sum, 32);
  const float inv = 1.0f/sum;

  {
    float* arow = outg + AOFF + (size_t)bh*Ln*Ln + (size_t)(i0+li)*Ln;
    #pragma unroll
    for (int jt=0; jt<32; ++jt){
      f32x4 p = acc[jt]*inv;
      acc[jt] = p;
      *(f32x4*)(arow + jt*16 + lq*4) = p;
    }
  }

  f32x4 oacc[4];
  #pragma unroll
  for (int dt=0; dt<4; ++dt) oacc[dt] = (f32x4)0.f;

  #pragma unroll
  for (int c=0; c<4; ++c){
    __syncthreads();
    #pragma unroll
    for (int it=0; it<2; ++it){
      const int j0 = (t>>4)*4 + it*64;
      const int d0 = (t&15)*4;
      const float* vr = vg + base + (size_t)(c*128 + j0)*Dn + d0;
      f32x4 r0 = *(const f32x4*)(vr);
      f32x4 r1 = *(const f32x4*)(vr + Dn);
      f32x4 r2 = *(const f32x4*)(vr + 2*Dn);
      f32x4 r3 = *(const f32x4*)(vr + 3*Dn);
      #pragma unroll
      for (int qd=0; qd<4; ++qd){
        u32x2 w; w.x = pack2(r0[qd], r1[qd]); w.y = pack2(r2[qd], r3[qd]);
        *(u32x2*)(VT + (d0+qd)*VTSTR + j0) = w;
      }
    }
    __syncthreads();
    #pragma unroll
    for (int jtl=0; jtl<8; ++jtl){
      const f32x4 p = acc[c*8+jtl];
      u32x2 w; w.x = pack2(p[0], p[1]); w.y = pack2(p[2], p[3]);
      *(u32x2*)(PW + li*FPSTRH + jtl*16 + lq*4) = w;
    }
    asm volatile("s_waitcnt lgkmcnt(0)" ::: "memory");
    #pragma unroll
    for (int c32=0; c32<4; ++c32){
      short8 pf = *(const short8*)(PW + li*FPSTRH + c32*32 + lq*8);
      #pragma unroll
      for (int dt=0; dt<4; ++dt){
        short8 vb = *(const short8*)(VT + (dt*16+li)*VTSTR + c32*32 + lq*8);
        oacc[dt] = __builtin_amdgcn_mfma_f32_16x16x32_bf16(vb, pf, oacc[dt], 0,0,0);
      }
    }
  }

  #pragma unroll
  for (int dt=0; dt<4; ++dt)
    *(f32x4*)(outg + base + (size_t)(i0+li)*Dn + dt*16 + lq*4) = oacc[dt];
}

extern "C" void kernel_launch(void* const* d_in, const int* in_sizes, int n_in,
                              void* d_out, int out_size, void* d_ws, size_t ws_size,
                              hipStream_t stream)
{
  (void)in_sizes; (void)n_in; (void)out_size;
  const float* qg = (const float*)d_in[0];
  const float* kg = (const float*)d_in[1];
  const float* vg = (const float*)d_in[2];
  const float* mg = (const float*)d_in[3];
  float* outg = (float*)d_out;

  const size_t WS_NEED = 25165824;   // KHI 8.39MB + KLO 8.39MB + VT 8.39MB
  if (d_ws && ws_size >= WS_NEED){
    uint16_t* khw = (uint16_t*)d_ws;
    uint16_t* klw = (uint16_t*)((char*)d_ws + 8388608);
    uint16_t* vtw = (uint16_t*)((char*)d_ws + 16777216);
    attn_prep<<<dim3(4, BHn), 256, 0, stream>>>(kg, vg, khw, klw, vtw);
    attn_main2<<<dim3(Ln/64, BHn), 256, 0, stream>>>(qg, mg, khw, klw, vtw, outg);
  } else {
    attn_mfma<<<dim3(Ln/64, BHn), 256, 0, stream>>>(qg, kg, vg, mg, outg);
  }
}

// Round 4
// 231.229 us; speedup vs baseline: 1.2732x; 1.0085x over previous
//
#include <hip/hip_runtime.h>
#include <stdint.h>

// B=16 H=8 L=512 D=64; fp32 in/out. out = concat(output[128,512,64], attn[128,512,512]).
// Round-8 (scheduling-only on round-7):
//  - attn stores interleaved into the PV loop; counted-vmcnt ledger invariant:
//    at each PV-chunk top the 8 newest vmem ops are prev chunk's stores, so
//    vmcnt(8) proves the needed V chunk landed while stores stay in flight.
//  - column-mask in LDS (CMV) -> softmax is lgkm/VALU only, no vmem drain.
//  - issueV(0) hoisted to QK chunk-2 close (buf0 free); QK c=3 waits vmcnt(4).
//  - Q/mask loads precede issueK(0) so compiler Q-waits leave DMA in flight.
//  - s_setprio(1) around MFMA clusters.
#define Ln 512
#define Dn 64
#define BHn 128
#define AOFF ((size_t)BHn*Ln*Dn)

typedef __attribute__((ext_vector_type(8))) short short8;   // 8 bf16 (4 VGPRs)
typedef __attribute__((ext_vector_type(4))) float f32x4;
typedef __attribute__((ext_vector_type(4))) unsigned int u32x4;
typedef __attribute__((ext_vector_type(2))) unsigned int u32x2;

__device__ __forceinline__ uint16_t f2bf(float f){
  uint32_t x = __float_as_uint(f);
  return (uint16_t)((x + 0x7FFFu + ((x>>16)&1u)) >> 16);   // RNE
}
__device__ __forceinline__ float bf2f(uint16_t u){ return __uint_as_float(((uint32_t)u)<<16); }
__device__ __forceinline__ uint32_t pack2(float a, float b){
  return (uint32_t)f2bf(a) | ((uint32_t)f2bf(b)<<16);
}
__device__ __forceinline__ void gld16(const uint16_t* g, uint16_t* l){
  __builtin_amdgcn_global_load_lds(
      (const __attribute__((address_space(1))) void*)g,
      (__attribute__((address_space(3))) void*)l, 16, 0, 0);
}

// ---- pre-pass: K -> KHI/KLO bf16, V -> V^T bf16, XOR-swizzled, chunk-major in ws ----
// K chunk layout (halves, per bh per chunk of 128 j): idx = j*64 + (k ^ ((j&7)<<3))
// V chunk layout (halves): idx = d*128 + (jl ^ ((d&7)<<3)), jl = j within chunk
extern "C" __global__ __launch_bounds__(256)
void attn_prep(const float* __restrict__ kg, const float* __restrict__ vg,
               uint16_t* __restrict__ khw, uint16_t* __restrict__ klw,
               uint16_t* __restrict__ vtw)
{
  const int t  = threadIdx.x;
  const int c  = blockIdx.x;          // j-chunk of 128
  const int bh = blockIdx.y;
  const size_t base = (size_t)bh*(Ln*Dn);
  const size_t wsb  = ((size_t)bh<<15) + ((size_t)c<<13);   // chunk base (halves)

  // K: thread pair per row; skh selects 32-k half
  {
    const int sj  = t>>1, skh = t&1;
    const float* kr = kg + base + (size_t)(c*128 + sj)*Dn + skh*32;
    const int sx = (sj&7)<<3;
    #pragma unroll
    for (int w2=0; w2<4; ++w2){
      f32x4 x0 = *(const f32x4*)(kr + w2*8);
      f32x4 x1 = *(const f32x4*)(kr + w2*8 + 4);
      uint32_t hw[4], lw[4];
      #pragma unroll
      for (int pi=0; pi<4; ++pi){
        float a0 = (pi<2) ? x0[pi*2]   : x1[(pi-2)*2];
        float a1 = (pi<2) ? x0[pi*2+1] : x1[(pi-2)*2+1];
        uint16_t h0 = f2bf(a0), h1 = f2bf(a1);
        hw[pi] = (uint32_t)h0 | ((uint32_t)h1<<16);
        lw[pi] = (uint32_t)f2bf(a0 - bf2f(h0)) | ((uint32_t)f2bf(a1 - bf2f(h1))<<16);
      }
      const size_t di = wsb + sj*64 + ((skh*32 + w2*8) ^ sx);
      *(u32x4*)(khw + di) = (u32x4){hw[0],hw[1],hw[2],hw[3]};
      *(u32x4*)(klw + di) = (u32x4){lw[0],lw[1],lw[2],lw[3]};
    }
  }

  // V: 4x4 register transpose -> VT[d][jl], swizzled
  #pragma unroll
  for (int it=0; it<2; ++it){
    const int j0 = (t>>4)*4 + it*64;    // [0,128)
    const int d0 = (t&15)*4;
    const float* vr = vg + base + (size_t)(c*128 + j0)*Dn + d0;
    f32x4 r0 = *(const f32x4*)(vr);
    f32x4 r1 = *(const f32x4*)(vr + Dn);
    f32x4 r2 = *(const f32x4*)(vr + 2*Dn);
    f32x4 r3 = *(const f32x4*)(vr + 3*Dn);
    #pragma unroll
    for (int qd=0; qd<4; ++qd){
      const int d = d0 + qd;
      u32x2 w; w.x = pack2(r0[qd], r1[qd]); w.y = pack2(r2[qd], r3[qd]);
      *(u32x2*)(vtw + wsb + d*128 + (j0 ^ ((d&7)<<3))) = w;
    }
  }
}

// ---- main: 64 q-rows/block, 4 waves x 16 rows; DMA-staged dbuf chunks ----
extern "C" __global__ __launch_bounds__(256, 2)
void attn_main2(const float* __restrict__ qg, const float* __restrict__ mg,
                const uint16_t* __restrict__ khw, const uint16_t* __restrict__ klw,
                const uint16_t* __restrict__ vtw, float* __restrict__ outg)
{
  // 64KB BIG: QK phase KH0[8192] KL0[8192] KH1[8192] KL1[8192] (halves)
  //           PV phase VT0[8192] VT1[8192] P[4 waves][2176]
  // + CMV[512] f32 column-mask terms (lgkm domain; keeps softmax off vmem)
  __shared__ __align__(16) uint16_t BIG[32768];
  __shared__ float CMV[512];

  const int t    = threadIdx.x;
  const int lane = t & 63;
  const int wv   = t >> 6;
  const int li   = lane & 15;
  const int lq   = lane >> 4;
  const int kx   = (li&7)<<3;          // swizzle XOR (halves)

  // XCD swizzle: lin%8 = XCD; XCD k owns bh [k*16,k*16+16)
  const int lin = blockIdx.x + (blockIdx.y << 3);
  const int xcd = lin & 7;
  const int jj  = lin >> 3;
  const int bh  = (xcd << 4) + (jj >> 3);
  const int b   = bh >> 3;
  const int i0  = (jj & 7)*64 + wv*16;

  const size_t base = (size_t)bh*(Ln*Dn);
  const float* mrow = mg + b*Ln;
  const size_t wsbh = (size_t)bh << 15;

  uint16_t* PW = BIG + 16384 + wv*2176;

  auto issueK = [&](int c, int bsel){
    const size_t so = wsbh + ((size_t)c<<13) + (wv<<11) + (lane<<3);
    uint16_t* dh = BIG + bsel*16384 + (wv<<11);
    #pragma unroll
    for (int i=0;i<4;++i){
      gld16(khw + so + i*512, dh + i*512);
      gld16(klw + so + i*512, dh + 8192 + i*512);
    }
  };
  auto issueV = [&](int c, int bsel){
    const size_t so = wsbh + ((size_t)c<<13) + (wv<<11) + (lane<<3);
    uint16_t* dv = BIG + bsel*8192 + (wv<<11);
    #pragma unroll
    for (int i=0;i<4;++i) gld16(vtw + so + i*512, dv + i*512);
  };

  // ---- prologue: Q + mask loads FIRST, then chunk-0 DMA (Q-waits leave DMA alive) ----
  const float* qrow = qg + base + (size_t)(i0 + li)*Dn;
  f32x4 qx0a = *(const f32x4*)(qrow + lq*8);
  f32x4 qx0b = *(const f32x4*)(qrow + lq*8 + 4);
  f32x4 qx1a = *(const f32x4*)(qrow + 32 + lq*8);
  f32x4 qx1b = *(const f32x4*)(qrow + 32 + lq*8 + 4);
  float m0 = mrow[t], m1 = mrow[t+256];
  float mv = mrow[i0 + li];

  issueK(0, 0);

  CMV[t]     = (m0 < -9000.f) ? 1e9f : m0;
  CMV[t+256] = (m1 < -9000.f) ? 1e9f : m1;
  const float rmv = (mv < -9000.f) ? 1e9f : mv;

  short8 qhi[2], qlo[2];
  #pragma unroll
  for (int kt=0; kt<2; ++kt){
    f32x4 xa = kt ? qx1a : qx0a;
    f32x4 xb = kt ? qx1b : qx0b;
    #pragma unroll
    for (int e=0; e<8; ++e){
      float x = (e<4) ? xa[e] : xb[e-4];
      uint16_t h = f2bf(x);
      qhi[kt][e] = (short)h;
      qlo[kt][e] = (short)f2bf(x - bf2f(h));
    }
  }

  f32x4 acc[32];
  #pragma unroll
  for (int j=0; j<32; ++j) acc[j] = (f32x4)0.f;

  // ---- QK: 4 chunks, double-buffered DMA; raw barriers + counted vmcnt ----
  #pragma unroll
  for (int c=0; c<4; ++c){
    if (c<3) issueK(c+1, (c+1)&1);
    if (c<3) asm volatile("s_waitcnt vmcnt(8)" ::: "memory");   // chunk c landed (mine)
    else     asm volatile("s_waitcnt vmcnt(4)" ::: "memory");   // K3 landed; V0 stays in flight
    __builtin_amdgcn_sched_barrier(0);
    __builtin_amdgcn_s_barrier();                                // all waves' portions landed
    __builtin_amdgcn_sched_barrier(0);
    const uint16_t* KHp = BIG + (c&1)*16384;
    const uint16_t* KLp = KHp + 8192;
    __builtin_amdgcn_s_setprio(1);
    #pragma unroll
    for (int jt=0; jt<8; ++jt){
      #pragma unroll
      for (int kt=0; kt<2; ++kt){
        const int idx = (jt*16 + li)*64 + ((kt*32 + lq*8) ^ kx);
        short8 kh = *(const short8*)(KHp + idx);
        short8 kl = *(const short8*)(KLp + idx);
        f32x4 A = acc[c*8+jt];
        A = __builtin_amdgcn_mfma_f32_16x16x32_bf16(kh, qhi[kt], A, 0,0,0);
        A = __builtin_amdgcn_mfma_f32_16x16x32_bf16(kl, qhi[kt], A, 0,0,0);
        A = __builtin_amdgcn_mfma_f32_16x16x32_bf16(kh, qlo[kt], A, 0,0,0);
        acc[c*8+jt] = A;
      }
    }
    __builtin_amdgcn_s_setprio(0);
    __builtin_amdgcn_sched_barrier(0);
    __builtin_amdgcn_s_barrier();                                // readers done before buf reuse
    __builtin_amdgcn_sched_barrier(0);
    if (c==2) issueV(0, 0);   // buf0 free after c=2 close; overlaps chunk-3 compute + softmax
  }

  // ---- mask + scale (CMV from LDS; pure lgkm/VALU — V0 DMA untouched) ----
  #pragma unroll
  for (int jt=0; jt<32; ++jt){
    f32x4 cm = *(const f32x4*)(CMV + jt*16 + lq*4);
    #pragma unroll
    for (int r=0; r<4; ++r)
      acc[jt][r] = (acc[jt][r]*0.125f - rmv) - cm[r];   // fp32 order matches ref
  }

  // ---- softmax over j (wave-local: lane owns full row across quads) ----
  float mx = -3.4e38f;
  #pragma unroll
  for (int jt=0; jt<32; ++jt)
    #pragma unroll
    for (int r=0; r<4; ++r) mx = fmaxf(mx, acc[jt][r]);
  mx = fmaxf(mx, __shfl_xor(mx, 16));
  mx = fmaxf(mx, __shfl_xor(mx, 32));
  float sum = 0.f;
  #pragma unroll
  for (int jt=0; jt<32; ++jt)
    #pragma unroll
    for (int r=0; r<4; ++r){ float e = __expf(acc[jt][r]-mx); acc[jt][r] = e; sum += e; }
  sum += __shfl_xor(sum, 16);
  sum += __shfl_xor(sum, 32);
  const float inv = 1.0f/sum;
  #pragma unroll
  for (int jt=0; jt<32; ++jt) acc[jt] = acc[jt]*inv;   // normalized P (also attn output)

  // ---- PV with per-chunk attn stores; ledger: 8 newest vmem = prev chunk's stores ----
  f32x4 oacc[4];
  #pragma unroll
  for (int dt=0; dt<4; ++dt) oacc[dt] = (f32x4)0.f;

  float* arow = outg + AOFF + (size_t)bh*Ln*Ln + (size_t)(i0+li)*Ln;

  #pragma unroll
  for (int c=0; c<4; ++c){
    if (c==0) asm volatile("s_waitcnt vmcnt(0)" ::: "memory");   // V0 landed (only V0 out)
    else      asm volatile("s_waitcnt vmcnt(8)" ::: "memory");   // V_c landed; prev stores fly
    __builtin_amdgcn_sched_barrier(0);
    __builtin_amdgcn_s_barrier();                                 // all waves; gates buf reuse
    __builtin_amdgcn_sched_barrier(0);
    if (c<3) issueV(c+1, (c+1)&1);
    #pragma unroll
    for (int jtl=0; jtl<8; ++jtl){                                // P chunk rows (wave-private)
      const f32x4 p = acc[c*8+jtl];
      u32x2 w; w.x = pack2(p[0], p[1]); w.y = pack2(p[2], p[3]);
      *(u32x2*)(PW + li*136 + jtl*16 + lq*4) = w;
    }
    asm volatile("s_waitcnt lgkmcnt(0)" ::: "memory");            // P visible within wave
    __builtin_amdgcn_sched_barrier(0);
    const uint16_t* VTp = BIG + (c&1)*8192;
    __builtin_amdgcn_s_setprio(1);
    #pragma unroll
    for (int c32=0; c32<4; ++c32){
      short8 pf = *(const short8*)(PW + li*136 + c32*32 + lq*8);           // P^T B-frag
      #pragma unroll
      for (int dt=0; dt<4; ++dt){
        short8 vb = *(const short8*)(VTp + (dt*16+li)*128 + ((c32*32+lq*8) ^ kx)); // V^T A-frag
        oacc[dt] = __builtin_amdgcn_mfma_f32_16x16x32_bf16(vb, pf, oacc[dt], 0,0,0);
      }
    }
    __builtin_amdgcn_s_setprio(0);
    // attn stores for chunk c (8 f32x4/lane) — overlap next chunk's wait/compute
    #pragma unroll
    for (int jtl=0; jtl<8; ++jtl)
      __builtin_nontemporal_store(acc[c*8+jtl], (f32x4*)(arow + (c*8+jtl)*16 + lq*4));
  }

  // ---- store O (O^T C-layout) ----
  #pragma unroll
  for (int dt=0; dt<4; ++dt)
    *(f32x4*)(outg + base + (size_t)(i0+li)*Dn + dt*16 + lq*4) = oacc[dt];
}

// ---------------- fallback (round-5 kernel) if workspace is too small ----------------
#define KSTR  72
#define VTSTR 136
#define FPSTRH 136

extern "C" __global__ __launch_bounds__(256, 2)
void attn_mfma(const float* __restrict__ qg, const float* __restrict__ kg,
               const float* __restrict__ vg, const float* __restrict__ mg,
               float* __restrict__ outg)
{
  __shared__ uint4 ldsraw[(36864 + 2048)/16];
  uint16_t* KHI = (uint16_t*)ldsraw;
  uint16_t* KLO = KHI + 128*KSTR;
  uint16_t* VT  = (uint16_t*)ldsraw;
  float*    CMV = (float*)((char*)ldsraw + 36864);

  const int t    = threadIdx.x;
  const int lane = t & 63;
  const int wv   = t >> 6;
  const int li   = lane & 15;
  const int lq   = lane >> 4;

  const int lin = blockIdx.x + (blockIdx.y << 3);
  const int xcd = lin & 7;
  const int jj  = lin >> 3;
  const int bh  = (xcd << 4) + (jj >> 3);
  const int b   = bh >> 3;
  const int i0  = (jj & 7)*64 + wv*16;

  const size_t base = (size_t)bh*(Ln*Dn);
  const float* mrow = mg + b*Ln;

  uint16_t* PW = (uint16_t*)((char*)ldsraw + 17408 + wv*(16*FPSTRH*2));

  {
    float m0 = mrow[t], m1 = mrow[t+256];
    CMV[t]     = (m0 < -9000.f) ? 1e9f : m0;
    CMV[t+256] = (m1 < -9000.f) ? 1e9f : m1;
  }

  short8 qhi[2], qlo[2];
  {
    const float* qrow = qg + base + (size_t)(i0 + li)*Dn;
    #pragma unroll
    for (int kt=0; kt<2; ++kt){
      const float* p = qrow + kt*32 + lq*8;
      f32x4 x0 = *(const f32x4*)p;
      f32x4 x1 = *(const f32x4*)(p+4);
      #pragma unroll
      for (int e=0; e<8; ++e){
        float x = (e<4) ? x0[e] : x1[e-4];
        uint16_t h = f2bf(x);
        qhi[kt][e] = (short)h;
        qlo[kt][e] = (short)f2bf(x - bf2f(h));
      }
    }
  }

  f32x4 acc[32];
  #pragma unroll
  for (int j=0; j<32; ++j) acc[j] = (f32x4)0.f;

  const int sj = t>>1, skh = t&1;
  #pragma unroll
  for (int c=0; c<4; ++c){
    __syncthreads();
    {
      const float* kr = kg + base + (size_t)(c*128 + sj)*Dn + skh*32;
      uint16_t* dhi = KHI + sj*KSTR + skh*32;
      uint16_t* dlo = KLO + sj*KSTR + skh*32;
      #pragma unroll
      for (int w2=0; w2<4; ++w2){
        f32x4 x0 = *(const f32x4*)(kr + w2*8);
        f32x4 x1 = *(const f32x4*)(kr + w2*8 + 4);
        uint32_t hw[4], lw[4];
        #pragma unroll
        for (int pi=0; pi<4; ++pi){
          float a0 = (pi<2) ? x0[pi*2]   : x1[(pi-2)*2];
          float a1 = (pi<2) ? x0[pi*2+1] : x1[(pi-2)*2+1];
          uint16_t h0 = f2bf(a0), h1 = f2bf(a1);
          hw[pi] = (uint32_t)h0 | ((uint32_t)h1<<16);
          lw[pi] = (uint32_t)f2bf(a0 - bf2f(h0)) | ((uint32_t)f2bf(a1 - bf2f(h1))<<16);
        }
        *(u32x4*)(dhi + w2*8) = (u32x4){hw[0],hw[1],hw[2],hw[3]};
        *(u32x4*)(dlo + w2*8) = (u32x4){lw[0],lw[1],lw[2],lw[3]};
      }
    }
    __syncthreads();
    #pragma unroll
    for (int jt=0; jt<8; ++jt){
      #pragma unroll
      for (int kt=0; kt<2; ++kt){
        const int off = (jt*16 + li)*KSTR + kt*32 + lq*8;
        short8 kh = *(const short8*)(KHI + off);
        short8 kl = *(const short8*)(KLO + off);
        f32x4 A = acc[c*8+jt];
        A = __builtin_amdgcn_mfma_f32_16x16x32_bf16(kh, qhi[kt], A, 0,0,0);
        A = __builtin_amdgcn_mfma_f32_16x16x32_bf16(kl, qhi[kt], A, 0,0,0);
        A = __builtin_amdgcn_mfma_f32_16x16x32_bf16(kh, qlo[kt], A, 0,0,0);
        acc[c*8+jt] = A;
      }
    }
  }

  {
    float mv = mrow[i0 + li];
    const float rmv = (mv < -9000.f) ? 1e9f : mv;
    #pragma unroll
    for (int jt=0; jt<32; ++jt){
      f32x4 cm = *(const f32x4*)(CMV + jt*16 + lq*4);
      #pragma unroll
      for (int r=0; r<4; ++r)
        acc[jt][r] = (acc[jt][r]*0.125f - rmv) - cm[r];
    }
  }
  float mx = -3.4e38f;
  #pragma unroll
  for (int jt=0; jt<32; ++jt)
    #pragma unroll
    for (int r=0; r<4; ++r) mx = fmaxf(mx, acc[jt][r]);
  mx = fmaxf(mx, __shfl_xor(mx, 16));
  mx = fmaxf(mx, __shfl_xor(mx, 32));
  float sum = 0.f;
  #pragma unroll
  for (int jt=0; jt<32; ++jt)
    #pragma unroll
    for (int r=0; r<4; ++r){ float e = __expf(acc[jt][r]-mx); acc[jt][r] = e; sum += e; }
  sum += __shfl_xor(sum, 16);
  sum += __shfl_xor(sum, 32);
  const float inv = 1.0f/sum;

  {
    float* arow = outg + AOFF + (size_t)bh*Ln*Ln + (size_t)(i0+li)*Ln;
    #pragma unroll
    for (int jt=0; jt<32; ++jt){
      f32x4 p = acc[jt]*inv;
      acc[jt] = p;
      *(f32x4*)(arow + jt*16 + lq*4) = p;
    }
  }

  f32x4 oacc[4];
  #pragma unroll
  for (int dt=0; dt<4; ++dt) oacc[dt] = (f32x4)0.f;

  #pragma unroll
  for (int c=0; c<4; ++c){
    __syncthreads();
    #pragma unroll
    for (int it=0; it<2; ++it){
      const int j0 = (t>>4)*4 + it*64;
      const int d0 = (t&15)*4;
      const float* vr = vg + base + (size_t)(c*128 + j0)*Dn + d0;
      f32x4 r0 = *(const f32x4*)(vr);
      f32x4 r1 = *(const f32x4*)(vr + Dn);
      f32x4 r2 = *(const f32x4*)(vr + 2*Dn);
      f32x4 r3 = *(const f32x4*)(vr + 3*Dn);
      #pragma unroll
      for (int qd=0; qd<4; ++qd){
        u32x2 w; w.x = pack2(r0[qd], r1[qd]); w.y = pack2(r2[qd], r3[qd]);
        *(u32x2*)(VT + (d0+qd)*VTSTR + j0) = w;
      }
    }
    __syncthreads();
    #pragma unroll
    for (int jtl=0; jtl<8; ++jtl){
      const f32x4 p = acc[c*8+jtl];
      u32x2 w; w.x = pack2(p[0], p[1]); w.y = pack2(p[2], p[3]);
      *(u32x2*)(PW + li*FPSTRH + jtl*16 + lq*4) = w;
    }
    asm volatile("s_waitcnt lgkmcnt(0)" ::: "memory");
    #pragma unroll
    for (int c32=0; c32<4; ++c32){
      short8 pf = *(const short8*)(PW + li*FPSTRH + c32*32 + lq*8);
      #pragma unroll
      for (int dt=0; dt<4; ++dt){
        short8 vb = *(const short8*)(VT + (dt*16+li)*VTSTR + c32*32 + lq*8);
        oacc[dt] = __builtin_amdgcn_mfma_f32_16x16x32_bf16(vb, pf, oacc[dt], 0,0,0);
      }
    }
  }

  #pragma unroll
  for (int dt=0; dt<4; ++dt)
    *(f32x4*)(outg + base + (size_t)(i0+li)*Dn + dt*16 + lq*4) = oacc[dt];
}

extern "C" void kernel_launch(void* const* d_in, const int* in_sizes, int n_in,
                              void* d_out, int out_size, void* d_ws, size_t ws_size,
                              hipStream_t stream)
{
  (void)in_sizes; (void)n_in; (void)out_size;
  const float* qg = (const float*)d_in[0];
  const float* kg = (const float*)d_in[1];
  const float* vg = (const float*)d_in[2];
  const float* mg = (const float*)d_in[3];
  float* outg = (float*)d_out;

  const size_t WS_NEED = 25165824;   // KHI 8.39MB + KLO 8.39MB + VT 8.39MB
  if (d_ws && ws_size >= WS_NEED){
    uint16_t* khw = (uint16_t*)d_ws;
    uint16_t* klw = (uint16_t*)((char*)d_ws + 8388608);
    uint16_t* vtw = (uint16_t*)((char*)d_ws + 16777216);
    attn_prep<<<dim3(4, BHn), 256, 0, stream>>>(kg, vg, khw, klw, vtw);
    attn_main2<<<dim3(Ln/64, BHn), 256, 0, stream>>>(qg, mg, khw, klw, vtw, outg);
  } else {
    attn_mfma<<<dim3(Ln/64, BHn), 256, 0, stream>>>(qg, kg, vg, mg, outg);
  }
}